// Round 7
// baseline (16300.449 us; speedup 1.0000x reference)
//
#include <hip/hip_runtime.h>

typedef _Float16 f16;
typedef _Float16 half8 __attribute__((ext_vector_type(8)));
typedef _Float16 half4v __attribute__((ext_vector_type(4)));
typedef float float4v __attribute__((ext_vector_type(4)));

constexpr int NB = 32;            // batch
constexpr int NT = 1024;          // time
constexpr int NH = 512;           // hidden
constexpr int NH3 = 1536;
constexpr int NM = NB * NT;       // 32768 rows
constexpr int CPB = 32;           // h-columns per block

// ---------------- init: zero h ping-pong buffers + flags ----------------
__global__ void init_hd(f16* __restrict__ hd, unsigned* __restrict__ flags) {
    int i = blockIdx.x * 256 + threadIdx.x;
    if (i < 2 * 2 * NB * NH) hd[i] = (f16)0.f;   // [dir][buf][NB][NH]
    if (i < 64) flags[i] = 0u;
}

// ---------------- fp32 -> fp16 convert ----------------
__global__ void cvt_f16(const float* __restrict__ src, f16* __restrict__ dst, int n4) {
    int i = blockIdx.x * blockDim.x + threadIdx.x;
    int stride = gridDim.x * blockDim.x;
    for (; i < n4; i += stride) {
        float4v v = *(const float4v*)(src + 4 * (size_t)i);
        half4v h;
        h[0] = (f16)v[0]; h[1] = (f16)v[1]; h[2] = (f16)v[2]; h[3] = (f16)v[3];
        *(half4v*)(dst + 4 * (size_t)i) = h;
    }
}

// ---------------- gi GEMM (unchanged) ----------------
__global__ __launch_bounds__(256, 2) void gemm_gi(
    const f16* __restrict__ A, const f16* __restrict__ Wf, const f16* __restrict__ Wr,
    const float* __restrict__ bf, const float* __restrict__ br,
    f16* __restrict__ gi, int K)
{
    __shared__ f16 As[128 * 72];
    __shared__ f16 Bs[128 * 72];
    const int m0 = blockIdx.x * 128;
    const int n0g = blockIdx.y * 128;
    const int dir = (n0g >= NH3) ? 1 : 0;
    const f16* __restrict__ W = dir ? Wr : Wf;
    const float* __restrict__ bias = dir ? br : bf;
    const int n0 = n0g - dir * NH3;
    const int tid = threadIdx.x;
    const int lane = tid & 63;
    const int wv = tid >> 6;
    const int wm = wv & 1;
    const int wn = wv >> 1;
    const int srow = tid >> 3;
    const int scol = (tid & 7) * 8;

    float4v acc[4][4] = {};
    for (int kb = 0; kb < K; kb += 64) {
        int4 av[4], bv[4];
#pragma unroll
        for (int i = 0; i < 4; i++) {
            av[i] = *(const int4*)(A + (size_t)(m0 + srow + i * 32) * K + kb + scol);
            bv[i] = *(const int4*)(W + (size_t)(n0 + srow + i * 32) * K + kb + scol);
        }
        __syncthreads();
#pragma unroll
        for (int i = 0; i < 4; i++) {
            *(int4*)(As + (srow + i * 32) * 72 + scol) = av[i];
            *(int4*)(Bs + (srow + i * 32) * 72 + scol) = bv[i];
        }
        __syncthreads();
#pragma unroll
        for (int ks = 0; ks < 2; ks++) {
            half8 af[4], bw[4];
#pragma unroll
            for (int i = 0; i < 4; i++) {
                af[i] = *(const half8*)(As + (wm * 64 + i * 16 + (lane & 15)) * 72 + ks * 32 + (lane >> 4) * 8);
                bw[i] = *(const half8*)(Bs + (wn * 64 + i * 16 + (lane & 15)) * 72 + ks * 32 + (lane >> 4) * 8);
            }
#pragma unroll
            for (int i = 0; i < 4; i++)
#pragma unroll
                for (int j = 0; j < 4; j++)
                    acc[i][j] = __builtin_amdgcn_mfma_f32_16x16x32_f16(af[i], bw[j], acc[i][j], 0, 0, 0);
        }
    }
    f16* __restrict__ gid = gi + (size_t)dir * NM * NH3;
#pragma unroll
    for (int i = 0; i < 4; i++) {
        const int m = m0 + wm * 64 + i * 16 + ((lane >> 4) << 2);
#pragma unroll
        for (int j = 0; j < 4; j++) {
            const int n = n0 + wn * 64 + j * 16 + (lane & 15);
            const float b = bias[n];
#pragma unroll
            for (int r = 0; r < 4; r++)
                gid[(size_t)(m + r) * NH3 + n] = (f16)(acc[i][j][r] + b);
        }
    }
}

// ---------------- device-coherent helpers ----------------
__device__ __forceinline__ unsigned long long ld_dev_u64(const void* p) {
    return __hip_atomic_load((const unsigned long long*)p,
                             __ATOMIC_RELAXED, __HIP_MEMORY_SCOPE_AGENT);
}
__device__ __forceinline__ void st_dev_u64(void* p, unsigned long long v) {
    __hip_atomic_store((unsigned long long*)p, v,
                       __ATOMIC_RELAXED, __HIP_MEMORY_SCOPE_AGENT);
}
__device__ __forceinline__ void st_dev_u32(void* p, unsigned v) {
    __hip_atomic_store((unsigned*)p, v,
                       __ATOMIC_RELAXED, __HIP_MEMORY_SCOPE_AGENT);
}

// ---------------- GRU scan ----------------
// grid = 32 blocks: blockIdx/16 = dir, blockIdx%16 = 32-col slice. 256 threads (4 waves).
// Per step: poll 16 monotonic flags (8 broadcast u64 loads) -> ONE coalesced coherent
// bulk read of h (16 u64/lane) shared across waves via LDS -> MFMA -> publish coalesced
// coherent u64 stores -> barrier (vmcnt drain) -> flag:=t+1.
__global__ __launch_bounds__(256, 1) void gru_scan(
    const f16* __restrict__ gi,      // [2][NM][1536]
    const f16* __restrict__ Whf, const f16* __restrict__ Whr,   // [1536][512]
    const float* __restrict__ bhf, const float* __restrict__ bhr,
    f16* __restrict__ HD,            // [2 dir][2 buf][NB][NH] f16 (pure data)
    unsigned* __restrict__ flags,    // [2 dir][16] u32, zero-initialized
    f16* __restrict__ y16,           // layer0 output (fp16) or nullptr
    float* __restrict__ y32,         // layer1 output (fp32, d_out) or nullptr
    float* __restrict__ hlast)       // [2][NB][NH] fp32
{
    __shared__ f16 Ht[32 * 520];             // h tile: row = batch (520-half padded row)
    __shared__ unsigned short Tt[32][36];    // transpose tile (row 72B, 8B-aligned)
    const int d = blockIdx.x >> 4;
    const int cs = blockIdx.x & 15;
    const int c0 = cs * CPB;
    const f16* __restrict__ W = d ? Whr : Whf;
    const float* __restrict__ bhh = d ? bhr : bhf;
    const int tid = threadIdx.x;
    const int lane = tid & 63;
    const int wv = tid >> 6;
    const int wm = wv & 1;          // batch half
    const int wn = wv >> 1;         // col half (16 cols)

    const int cl = c0 + wn * 16 + (lane & 15);     // output h-column
    const int bA = wm * 16 + (lane & 15);          // A-frag batch row
    const int bC = wm * 16 + ((lane >> 4) << 2);   // C-frag batch base (+r)

    // hoist B fragments straight from global (one-time, 48 x 16B per lane)
    half8 bfr[16][3];
#pragma unroll
    for (int kk = 0; kk < 16; kk++)
#pragma unroll
        for (int g = 0; g < 3; g++)
            bfr[kk][g] = *(const half8*)(W + (size_t)(g * 512 + cl) * 512 + kk * 32 + (lane >> 4) * 8);
    float bh[3];
#pragma unroll
    for (int g = 0; g < 3; g++) bh[g] = bhh[g * 512 + cl];

    unsigned* const myflag = flags + d * 16 + cs;
    const unsigned long long* const FQ = (const unsigned long long*)(flags + d * 16);
    const f16* __restrict__ giD = gi + (size_t)d * NM * NH3;

    float h32[4] = {0.f, 0.f, 0.f, 0.f};
    float gif[3][4];
    {
        const int te = d ? (NT - 1) : 0;
#pragma unroll
        for (int r = 0; r < 4; r++) {
            const f16* p = giD + ((size_t)(bC + r) * NT + te) * NH3;
#pragma unroll
            for (int g = 0; g < 3; g++) gif[g][r] = (float)p[g * 512 + cl];
        }
    }

    for (int t = 0; t < NT; t++) {
        const int te = d ? (NT - 1 - t) : t;

        // -------- poll: all 16 producer flags >= t (8 broadcast u64 loads) --------
        if (t > 0) {
            const unsigned target = (unsigned)t;
            bool ok;
            do {
                ok = true;
#pragma unroll
                for (int i = 0; i < 8; i++) {
                    const unsigned long long v = ld_dev_u64(FQ + i);
                    ok &= ((unsigned)v >= target) & ((unsigned)(v >> 32) >= target);
                }
            } while (!ok);
        }

        // -------- one-shot coalesced bulk read of gen-t h -> LDS --------
        // u64 #u of the [32][512]-f16 buffer holds batch u>>7, halves (u&127)*4
        // (128 u64 per 512-half row). R6 bug: used u>>6/u&63 -> LDS OOB + garbage.
        {
            const unsigned long long* HDr =
                (const unsigned long long*)(HD + (size_t)(d * 2 + (t & 1)) * NB * NH);
            unsigned long long hv[16];
#pragma unroll
            for (int k = 0; k < 16; k++)
                hv[k] = ld_dev_u64(HDr + tid + k * 256);
#pragma unroll
            for (int k = 0; k < 16; k++) {
                const int u = tid + k * 256;
                *(unsigned long long*)(Ht + (u >> 7) * 520 + (u & 127) * 4) = hv[k];
            }
        }
        __syncthreads();   // (A) h tile complete

        // -------- fragments + MFMA --------
        half8 afr[16];
#pragma unroll
        for (int kk = 0; kk < 16; kk++)
            afr[kk] = *(const half8*)(Ht + bA * 520 + kk * 32 + (lane >> 4) * 8);
        float4v acc[3] = {};
#pragma unroll
        for (int kk = 0; kk < 16; kk++)
#pragma unroll
            for (int g = 0; g < 3; g++)
                acc[g] = __builtin_amdgcn_mfma_f32_16x16x32_f16(afr[kk], bfr[kk][g], acc[g], 0, 0, 0);

        float hnew[4]; f16 hnew16[4];
#pragma unroll
        for (int r = 0; r < 4; r++) {
            const float hr = acc[0][r] + bh[0];
            const float hz = acc[1][r] + bh[1];
            const float hn = acc[2][r] + bh[2];
            const float rg = 1.f / (1.f + __expf(-(gif[0][r] + hr)));
            const float zg = 1.f / (1.f + __expf(-(gif[1][r] + hz)));
            const float x2 = gif[2][r] + rg * hn;
            const float e2 = __expf(x2 + x2);
            const float ng = 1.f - 2.f / (e2 + 1.f);
            const float h = (1.f - zg) * ng + zg * h32[r];
            h32[r] = h; hnew[r] = h; hnew16[r] = (f16)h;
        }

        const bool more = (t + 1 < NT);
        if (more) {
#pragma unroll
            for (int r = 0; r < 4; r++)
                Tt[bC + r][cl - c0] = __builtin_bit_cast(unsigned short, hnew16[r]);
            __syncthreads();   // (B) Tt complete
            // publish: each thread packs 4 cols of one batch row -> one coherent u64
            {
                const int b = tid >> 3, o = tid & 7;
                const unsigned long long v = *(const unsigned long long*)&Tt[b][o * 4];
                f16* HDw = HD + (size_t)(d * 2 + ((t + 1) & 1)) * NB * NH;
                st_dev_u64(HDw + b * 512 + c0 + o * 4, v);
            }
            __syncthreads();   // (C) vmcnt drain: h stores ACKed at coherence point;
                               //     also separates Tt/Ht reuse from next iteration
            if (tid == 0)
                st_dev_u32(myflag, (unsigned)(t + 1));
            // prefetch gi for t+1 (plain cached loads; overlap y-stores + next poll)
            const int te2 = d ? (NT - 2 - t) : (t + 1);
#pragma unroll
            for (int r = 0; r < 4; r++) {
                const f16* p = giD + ((size_t)(bC + r) * NT + te2) * NH3;
#pragma unroll
                for (int g = 0; g < 3; g++) gif[g][r] = (float)p[g * 512 + cl];
            }
        }
        // -------- y output (nontemporal streaming) --------
#pragma unroll
        for (int r = 0; r < 4; r++) {
            const size_t yoff = ((size_t)(bC + r) * NT + te) * (2 * NH) + d * NH + cl;
            if (y16) __builtin_nontemporal_store(hnew16[r], &y16[yoff]);
            else     __builtin_nontemporal_store(hnew[r], &y32[yoff]);
        }
        if (t == NT - 1) {
#pragma unroll
            for (int r = 0; r < 4; r++)
                hlast[d * NB * NH + (bC + r) * NH + cl] = hnew[r];
        }
    }
}

extern "C" void kernel_launch(void* const* d_in, const int* in_sizes, int n_in,
                              void* d_out, int out_size, void* d_ws, size_t ws_size,
                              hipStream_t stream) {
    (void)in_sizes; (void)n_in; (void)out_size; (void)ws_size;
    const float* X     = (const float*)d_in[0];
    const float* wih0f = (const float*)d_in[1];
    const float* bih0f = (const float*)d_in[2];
    const float* whh0f = (const float*)d_in[3];
    const float* bhh0f = (const float*)d_in[4];
    const float* wih0r = (const float*)d_in[5];
    const float* bih0r = (const float*)d_in[6];
    const float* whh0r = (const float*)d_in[7];
    const float* bhh0r = (const float*)d_in[8];
    const float* wih1f = (const float*)d_in[9];
    const float* bih1f = (const float*)d_in[10];
    const float* whh1f = (const float*)d_in[11];
    const float* bhh1f = (const float*)d_in[12];
    const float* wih1r = (const float*)d_in[13];
    const float* bih1r = (const float*)d_in[14];
    const float* whh1r = (const float*)d_in[15];
    const float* bhh1r = (const float*)d_in[16];

    char* ws = (char*)d_ws;
    f16* Xh   = (f16*)(ws + 0ull);
    f16* Wi0f = (f16*)(ws + 33554432ull);
    f16* Wi0r = (f16*)(ws + 35127296ull);
    f16* Wh0f = (f16*)(ws + 36700160ull);
    f16* Wh0r = (f16*)(ws + 38273024ull);
    f16* Wi1f = (f16*)(ws + 39845888ull);
    f16* Wi1r = (f16*)(ws + 42991616ull);
    f16* Wh1f = (f16*)(ws + 46137344ull);
    f16* Wh1r = (f16*)(ws + 47710208ull);
    f16* Y0h  = (f16*)(ws + 49283072ull);
    f16* HD   = (f16*)(ws + 116391936ull);             // 128KB ping-pong h
    unsigned* FLAGS = (unsigned*)(ws + 116523008ull);  // 2x16 u32
    f16* GI   = (f16*)(ws + 116655104ull);
    float* out = (float*)d_out;

    auto cvt = [&](const float* s, f16* d, size_t n) {
        int n4 = (int)(n / 4);
        int grid = (n4 + 255) / 256; if (grid > 4096) grid = 4096;
        cvt_f16<<<grid, 256, 0, stream>>>(s, d, n4);
    };
    cvt(X,     Xh,   (size_t)NM * NH);
    cvt(wih0f, Wi0f, (size_t)NH3 * NH);
    cvt(wih0r, Wi0r, (size_t)NH3 * NH);
    cvt(whh0f, Wh0f, (size_t)NH3 * NH);
    cvt(whh0r, Wh0r, (size_t)NH3 * NH);
    cvt(wih1f, Wi1f, (size_t)NH3 * 2 * NH);
    cvt(wih1r, Wi1r, (size_t)NH3 * 2 * NH);
    cvt(whh1f, Wh1f, (size_t)NH3 * NH);
    cvt(whh1r, Wh1r, (size_t)NH3 * NH);

    const size_t OUT0 = (size_t)NM * 2 * NH;   // 33,554,432 floats

    // Layer 0
    init_hd<<<256, 256, 0, stream>>>(HD, FLAGS);
    gemm_gi<<<dim3(NM / 128, 24), 256, 0, stream>>>(Xh, Wi0f, Wi0r, bih0f, bih0r, GI, NH);
    gru_scan<<<32, 256, 0, stream>>>(GI, Wh0f, Wh0r, bhh0f, bhh0r,
                                     HD, FLAGS, Y0h, nullptr, out + OUT0);
    // Layer 1
    init_hd<<<256, 256, 0, stream>>>(HD, FLAGS);
    gemm_gi<<<dim3(NM / 128, 24), 256, 0, stream>>>(Y0h, Wi1f, Wi1r, bih1f, bih1r, GI, 2 * NH);
    gru_scan<<<32, 256, 0, stream>>>(GI, Wh1f, Wh1r, bhh1f, bhh1r,
                                     HD, FLAGS, nullptr, out, out + OUT0 + 2 * NB * NH);
}

// Round 8
// 12943.651 us; speedup vs baseline: 1.2593x; 1.2593x over previous
//
#include <hip/hip_runtime.h>

typedef _Float16 f16;
typedef _Float16 half8 __attribute__((ext_vector_type(8)));
typedef _Float16 half4v __attribute__((ext_vector_type(4)));
typedef float float4v __attribute__((ext_vector_type(4)));

constexpr int NB = 32;            // batch
constexpr int NT = 1024;          // time
constexpr int NH = 512;           // hidden
constexpr int NH3 = 1536;
constexpr int NM = NB * NT;       // 32768 rows

// Tagged h-exchange buffer: HB[dir][buf][slice 32][batch 32][chunk 6] u64.
// Chunk = 3 f16 payload | 16-bit generation tag (bits 48..63). One aligned 8B
// store => tag+data atomic. 192KB total, re-zeroed between layers.
constexpr int HB_U64 = 2 * 2 * 32 * 32 * 6;   // 24576

// ---------------- init: zero tagged exchange buffer ----------------
__global__ void init_hb(unsigned long long* __restrict__ hb) {
    int i = blockIdx.x * 256 + threadIdx.x;
    if (i < HB_U64) hb[i] = 0ull;
}

// ---------------- fp32 -> fp16 convert ----------------
__global__ void cvt_f16(const float* __restrict__ src, f16* __restrict__ dst, int n4) {
    int i = blockIdx.x * blockDim.x + threadIdx.x;
    int stride = gridDim.x * blockDim.x;
    for (; i < n4; i += stride) {
        float4v v = *(const float4v*)(src + 4 * (size_t)i);
        half4v h;
        h[0] = (f16)v[0]; h[1] = (f16)v[1]; h[2] = (f16)v[2]; h[3] = (f16)v[3];
        *(half4v*)(dst + 4 * (size_t)i) = h;
    }
}

// ---------------- gi GEMM (unchanged) ----------------
__global__ __launch_bounds__(256, 2) void gemm_gi(
    const f16* __restrict__ A, const f16* __restrict__ Wf, const f16* __restrict__ Wr,
    const float* __restrict__ bf, const float* __restrict__ br,
    f16* __restrict__ gi, int K)
{
    __shared__ f16 As[128 * 72];
    __shared__ f16 Bs[128 * 72];
    const int m0 = blockIdx.x * 128;
    const int n0g = blockIdx.y * 128;
    const int dir = (n0g >= NH3) ? 1 : 0;
    const f16* __restrict__ W = dir ? Wr : Wf;
    const float* __restrict__ bias = dir ? br : bf;
    const int n0 = n0g - dir * NH3;
    const int tid = threadIdx.x;
    const int lane = tid & 63;
    const int wv = tid >> 6;
    const int wm = wv & 1;
    const int wn = wv >> 1;
    const int srow = tid >> 3;
    const int scol = (tid & 7) * 8;

    float4v acc[4][4] = {};
    for (int kb = 0; kb < K; kb += 64) {
        int4 av[4], bv[4];
#pragma unroll
        for (int i = 0; i < 4; i++) {
            av[i] = *(const int4*)(A + (size_t)(m0 + srow + i * 32) * K + kb + scol);
            bv[i] = *(const int4*)(W + (size_t)(n0 + srow + i * 32) * K + kb + scol);
        }
        __syncthreads();
#pragma unroll
        for (int i = 0; i < 4; i++) {
            *(int4*)(As + (srow + i * 32) * 72 + scol) = av[i];
            *(int4*)(Bs + (srow + i * 32) * 72 + scol) = bv[i];
        }
        __syncthreads();
#pragma unroll
        for (int ks = 0; ks < 2; ks++) {
            half8 af[4], bw[4];
#pragma unroll
            for (int i = 0; i < 4; i++) {
                af[i] = *(const half8*)(As + (wm * 64 + i * 16 + (lane & 15)) * 72 + ks * 32 + (lane >> 4) * 8);
                bw[i] = *(const half8*)(Bs + (wn * 64 + i * 16 + (lane & 15)) * 72 + ks * 32 + (lane >> 4) * 8);
            }
#pragma unroll
            for (int i = 0; i < 4; i++)
#pragma unroll
                for (int j = 0; j < 4; j++)
                    acc[i][j] = __builtin_amdgcn_mfma_f32_16x16x32_f16(af[i], bw[j], acc[i][j], 0, 0, 0);
        }
    }
    f16* __restrict__ gid = gi + (size_t)dir * NM * NH3;
#pragma unroll
    for (int i = 0; i < 4; i++) {
        const int m = m0 + wm * 64 + i * 16 + ((lane >> 4) << 2);
#pragma unroll
        for (int j = 0; j < 4; j++) {
            const int n = n0 + wn * 64 + j * 16 + (lane & 15);
            const float b = bias[n];
#pragma unroll
            for (int r = 0; r < 4; r++)
                gid[(size_t)(m + r) * NH3 + n] = (f16)(acc[i][j][r] + b);
        }
    }
}

// ---------------- device-coherent helpers ----------------
__device__ __forceinline__ unsigned long long ld_dev_u64(const void* p) {
    return __hip_atomic_load((const unsigned long long*)p,
                             __ATOMIC_RELAXED, __HIP_MEMORY_SCOPE_AGENT);
}
__device__ __forceinline__ void st_dev_u64(void* p, unsigned long long v) {
    __hip_atomic_store((unsigned long long*)p, v,
                       __ATOMIC_RELAXED, __HIP_MEMORY_SCOPE_AGENT);
}

union U4H8 { unsigned u[4]; half8 h; };

// ---------------- GRU scan ----------------
// grid = 64 blocks: blockIdx/32 = dir, blockIdx%32 = 16-col slice. 128 threads (2 waves).
// h exchange is TAGGED PAYLOAD (R5): 8B chunk = 3 f16 + generation tag, one relaxed
// agent store; detection completes WITH the data in registers (1 coherent RT).
// NEW vs R5: (a) SELECTIVE RELOAD - spin re-reads only chunks whose tag is stale,
// instead of re-sweeping all 48KB every iteration (the measured 6-sweep congestion);
// (b) double-buffered transpose tile -> one barrier per step instead of two.
__global__ __launch_bounds__(128, 1) void gru_scan(
    const f16* __restrict__ gi,      // [2][NM][1536]
    const f16* __restrict__ Whf, const f16* __restrict__ Whr,   // [1536][512]
    const float* __restrict__ bhf, const float* __restrict__ bhr,
    unsigned long long* __restrict__ HB,   // [2][2][32][32][6] tagged chunks
    f16* __restrict__ y16,           // layer0 output (fp16) or nullptr
    float* __restrict__ y32,         // layer1 output (fp32, d_out) or nullptr
    float* __restrict__ hlast)       // [2][NB][NH] fp32
{
    __shared__ f16 Wlds[48 * 520];
    __shared__ unsigned short Tt[2][32][18];   // double-buffered transpose tile
    const int d = blockIdx.x >> 5;
    const int cs = blockIdx.x & 31;
    const int c0 = cs * 16;
    const f16* __restrict__ W = d ? Whr : Whf;
    const float* __restrict__ bhh = d ? bhr : bhf;
    const int tid = threadIdx.x;
    const int lane = tid & 63;
    const int mt = tid >> 6;         // wave index = batch half

    // stage W_hh rows {g*512 + c0 + j} into LDS (row-major [48][520], padded)
    for (int c = tid; c < 48 * 64; c += 128) {
        const int row = c >> 6;
        const int off = (c & 63) * 8;
        const int g = row >> 4, j = row & 15;
        *(int4*)(Wlds + row * 520 + off) = *(const int4*)(W + (size_t)(g * 512 + c0 + j) * 512 + off);
    }
    if (tid < 64) {   // zero pad columns of both Tt buffers
        Tt[0][tid >> 1][16 + (tid & 1)] = 0;
        Tt[1][tid >> 1][16 + (tid & 1)] = 0;
    }
    const int cl = c0 + (lane & 15);
    float bh[3];
#pragma unroll
    for (int g = 0; g < 3; g++) bh[g] = bhh[g * 512 + cl];
    __syncthreads();

    // hoist B fragments (step-invariant): 48 x half8
    half8 bfr[16][3];
#pragma unroll
    for (int kk = 0; kk < 16; kk++)
#pragma unroll
        for (int g = 0; g < 3; g++)
            bfr[kk][g] = *(const half8*)(Wlds + (g * 16 + (lane & 15)) * 520 + kk * 32 + (lane >> 4) * 8);

    const f16* __restrict__ giD = gi + (size_t)d * NM * NH3;
    const int bA = mt * 16 + (lane & 15);          // A-frag row (batch)
    const int bC = mt * 16 + ((lane >> 4) << 2);   // C-frag batch base (+r)
    const int g0 = (lane >> 4) & 1;                // which 8-half group
    const int csBase = (lane >> 4) >> 1;           // slice parity
    const int chunkBase = (csBase * 32 + bA) * 6 + g0 * 3;

    float h32[4] = {0.f, 0.f, 0.f, 0.f};
    float gif[3][4];
    {
        const int te = d ? (NT - 1) : 0;
#pragma unroll
        for (int r = 0; r < 4; r++) {
            const f16* p = giD + ((size_t)(bC + r) * NT + te) * NH3;
#pragma unroll
            for (int g = 0; g < 3; g++) gif[g][r] = (float)p[g * 512 + cl];
        }
    }

    for (int t = 0; t < NT; t++) {
        const int te = d ? (NT - 1 - t) : t;
        const unsigned long long* const HBr = HB + (size_t)(d * 2 + (t & 1)) * 6144;
        const unsigned tagT = (unsigned)t & 0xffffu;

        // -------- poll with SELECTIVE reload: first sweep loads all 48 chunks;
        // subsequent sweeps re-load only chunks whose tag is stale (exec-masked).
        unsigned long long ch[16][3];
#pragma unroll
        for (int kk = 0; kk < 16; kk++) {
            const unsigned long long* p = HBr + chunkBase + kk * 384;
            ch[kk][0] = ld_dev_u64(p);
            ch[kk][1] = ld_dev_u64(p + 1);
            ch[kk][2] = ld_dev_u64(p + 2);
        }
        while (true) {
            unsigned bad = 0;
#pragma unroll
            for (int kk = 0; kk < 16; kk++)
#pragma unroll
                for (int ci = 0; ci < 3; ci++)
                    bad |= (unsigned)(ch[kk][ci] >> 48) ^ tagT;
            if (__all(bad == 0)) break;
#pragma unroll
            for (int kk = 0; kk < 16; kk++) {
                const unsigned long long* p = HBr + chunkBase + kk * 384;
#pragma unroll
                for (int ci = 0; ci < 3; ci++)
                    if ((unsigned)(ch[kk][ci] >> 48) != tagT)
                        ch[kk][ci] = ld_dev_u64(p + ci);
            }
        }

        // -------- extract fragments + MFMA --------
        float4v acc[3] = {};
#pragma unroll
        for (int kk = 0; kk < 16; kk++) {
            const unsigned A_lo = (unsigned)ch[kk][0], A_hi = (unsigned)(ch[kk][0] >> 32);
            const unsigned B_lo = (unsigned)ch[kk][1], B_hi = (unsigned)(ch[kk][1] >> 32);
            const unsigned C_lo = (unsigned)ch[kk][2];
            U4H8 u;
            u.u[0] = A_lo;
            u.u[1] = (A_hi & 0xffffu) | (B_lo << 16);
            u.u[2] = (B_lo >> 16) | (B_hi << 16);
            u.u[3] = C_lo;
#pragma unroll
            for (int g = 0; g < 3; g++)
                acc[g] = __builtin_amdgcn_mfma_f32_16x16x32_f16(u.h, bfr[kk][g], acc[g], 0, 0, 0);
        }

        float hnew[4]; f16 hnew16[4];
#pragma unroll
        for (int r = 0; r < 4; r++) {
            const float hr = acc[0][r] + bh[0];
            const float hz = acc[1][r] + bh[1];
            const float hn = acc[2][r] + bh[2];
            const float rg = 1.f / (1.f + __expf(-(gif[0][r] + hr)));
            const float zg = 1.f / (1.f + __expf(-(gif[1][r] + hz)));
            const float x2 = gif[2][r] + rg * hn;
            const float e2 = __expf(x2 + x2);
            const float ng = 1.f - 2.f / (e2 + 1.f);
            const float h = (1.f - zg) * ng + zg * h32[r];
            h32[r] = h; hnew[r] = h; hnew16[r] = (f16)h;
        }

        const bool more = (t + 1 < NT);
        if (more) {
            // -------- publish h_{t+1}: LDS transpose (dbuf) -> 192 tagged u64 --------
            const int tb = (t + 1) & 1;
#pragma unroll
            for (int r = 0; r < 4; r++)
                Tt[tb][bC + r][lane & 15] = __builtin_bit_cast(unsigned short, hnew16[r]);
            __syncthreads();   // Tt[tb] complete (only barrier in the loop)
            {
                const unsigned long long tagw = ((unsigned long long)((t + 1) & 0xffff)) << 48;
                unsigned long long* const HBw =
                    HB + (size_t)(d * 2 + tb) * 6144 + (size_t)cs * 192;
#pragma unroll
                for (int s = 0; s < 2; s++) {
                    const int cf = tid + s * 128;
                    if (cf < 192) {
                        const int b = cf / 6, c = cf % 6;
                        const int j0 = (c / 3) * 8 + (c % 3) * 3;
                        const unsigned long long h0 = Tt[tb][b][j0];
                        const unsigned long long h1 = Tt[tb][b][j0 + 1];
                        const unsigned long long h2 = Tt[tb][b][j0 + 2];
                        st_dev_u64(HBw + cf, h0 | (h1 << 16) | (h2 << 32) | tagw);
                    }
                }
            }
            // no second barrier: next iteration writes Tt[tb^1] (double buffer)
        }
        // -------- y output (nontemporal streaming; overlaps peers' polling) --------
#pragma unroll
        for (int r = 0; r < 4; r++) {
            const size_t yoff = ((size_t)(bC + r) * NT + te) * (2 * NH) + d * NH + cl;
            if (y16) __builtin_nontemporal_store(hnew16[r], &y16[yoff]);
            else     __builtin_nontemporal_store(hnew[r], &y32[yoff]);
        }
        if (t == NT - 1) {
#pragma unroll
            for (int r = 0; r < 4; r++)
                hlast[d * NB * NH + (bC + r) * NH + cl] = hnew[r];
        }
        if (more) {
            // prefetch gi for t+1 (plain cached; in flight during next poll)
            const int te2 = d ? (NT - 2 - t) : (t + 1);
#pragma unroll
            for (int r = 0; r < 4; r++) {
                const f16* p = giD + ((size_t)(bC + r) * NT + te2) * NH3;
#pragma unroll
                for (int g = 0; g < 3; g++) gif[g][r] = (float)p[g * 512 + cl];
            }
        }
    }
}

extern "C" void kernel_launch(void* const* d_in, const int* in_sizes, int n_in,
                              void* d_out, int out_size, void* d_ws, size_t ws_size,
                              hipStream_t stream) {
    (void)in_sizes; (void)n_in; (void)out_size; (void)ws_size;
    const float* X     = (const float*)d_in[0];
    const float* wih0f = (const float*)d_in[1];
    const float* bih0f = (const float*)d_in[2];
    const float* whh0f = (const float*)d_in[3];
    const float* bhh0f = (const float*)d_in[4];
    const float* wih0r = (const float*)d_in[5];
    const float* bih0r = (const float*)d_in[6];
    const float* whh0r = (const float*)d_in[7];
    const float* bhh0r = (const float*)d_in[8];
    const float* wih1f = (const float*)d_in[9];
    const float* bih1f = (const float*)d_in[10];
    const float* whh1f = (const float*)d_in[11];
    const float* bhh1f = (const float*)d_in[12];
    const float* wih1r = (const float*)d_in[13];
    const float* bih1r = (const float*)d_in[14];
    const float* whh1r = (const float*)d_in[15];
    const float* bhh1r = (const float*)d_in[16];

    char* ws = (char*)d_ws;
    f16* Xh   = (f16*)(ws + 0ull);
    f16* Wi0f = (f16*)(ws + 33554432ull);
    f16* Wi0r = (f16*)(ws + 35127296ull);
    f16* Wh0f = (f16*)(ws + 36700160ull);
    f16* Wh0r = (f16*)(ws + 38273024ull);
    f16* Wi1f = (f16*)(ws + 39845888ull);
    f16* Wi1r = (f16*)(ws + 42991616ull);
    f16* Wh1f = (f16*)(ws + 46137344ull);
    f16* Wh1r = (f16*)(ws + 47710208ull);
    f16* Y0h  = (f16*)(ws + 49283072ull);
    unsigned long long* HBu = (unsigned long long*)(ws + 116391936ull);  // 192KB
    f16* GI   = (f16*)(ws + 116655104ull);
    float* out = (float*)d_out;

    auto cvt = [&](const float* s, f16* d, size_t n) {
        int n4 = (int)(n / 4);
        int grid = (n4 + 255) / 256; if (grid > 4096) grid = 4096;
        cvt_f16<<<grid, 256, 0, stream>>>(s, d, n4);
    };
    cvt(X,     Xh,   (size_t)NM * NH);
    cvt(wih0f, Wi0f, (size_t)NH3 * NH);
    cvt(wih0r, Wi0r, (size_t)NH3 * NH);
    cvt(whh0f, Wh0f, (size_t)NH3 * NH);
    cvt(whh0r, Wh0r, (size_t)NH3 * NH);
    cvt(wih1f, Wi1f, (size_t)NH3 * 2 * NH);
    cvt(wih1r, Wi1r, (size_t)NH3 * 2 * NH);
    cvt(whh1f, Wh1f, (size_t)NH3 * NH);
    cvt(whh1r, Wh1r, (size_t)NH3 * NH);

    const size_t OUT0 = (size_t)NM * 2 * NH;   // 33,554,432 floats

    // Layer 0
    init_hb<<<96, 256, 0, stream>>>(HBu);
    gemm_gi<<<dim3(NM / 128, 24), 256, 0, stream>>>(Xh, Wi0f, Wi0r, bih0f, bih0r, GI, NH);
    gru_scan<<<64, 128, 0, stream>>>(GI, Wh0f, Wh0r, bhh0f, bhh0r,
                                     HBu, Y0h, nullptr, out + OUT0);
    // Layer 1 (reset tags, reuse HB)
    init_hb<<<96, 256, 0, stream>>>(HBu);
    gemm_gi<<<dim3(NM / 128, 24), 256, 0, stream>>>(Y0h, Wi1f, Wi1r, bih1f, bih1r, GI, 2 * NH);
    gru_scan<<<64, 128, 0, stream>>>(GI, Wh1f, Wh1r, bhh1f, bhh1r,
                                     HBu, nullptr, out, out + OUT0 + 2 * NB * NH);
}

// Round 10
// 12243.122 us; speedup vs baseline: 1.3314x; 1.0572x over previous
//
#include <hip/hip_runtime.h>

typedef _Float16 f16;
typedef _Float16 half8 __attribute__((ext_vector_type(8)));
typedef _Float16 half4v __attribute__((ext_vector_type(4)));
typedef float float4v __attribute__((ext_vector_type(4)));

constexpr int NB = 32;            // batch
constexpr int NT = 1024;          // time
constexpr int NH = 512;           // hidden
constexpr int NH3 = 1536;
constexpr int NM = NB * NT;       // 32768 rows

// Tagged h-exchange buffer: HB[dir][buf][slice 32][batch 32][chunk 6] u64.
// Chunk = 3 f16 payload | 16-bit generation tag (bits 48..63). One aligned 8B
// store => tag+data atomic. 192KB total, re-zeroed between layers (tag 0 == h0=0).
constexpr int HB_U64 = 2 * 2 * 32 * 32 * 6;   // 24576

__global__ void init_hb(unsigned long long* __restrict__ hb) {
    int i = blockIdx.x * 256 + threadIdx.x;
    if (i < HB_U64) hb[i] = 0ull;
}

// ---------------- fp32 -> fp16 convert ----------------
__global__ void cvt_f16(const float* __restrict__ src, f16* __restrict__ dst, int n4) {
    int i = blockIdx.x * blockDim.x + threadIdx.x;
    int stride = gridDim.x * blockDim.x;
    for (; i < n4; i += stride) {
        float4v v = *(const float4v*)(src + 4 * (size_t)i);
        half4v h;
        h[0] = (f16)v[0]; h[1] = (f16)v[1]; h[2] = (f16)v[2]; h[3] = (f16)v[3];
        *(half4v*)(dst + 4 * (size_t)i) = h;
    }
}

// ---------------- gi GEMM (unchanged) ----------------
__global__ __launch_bounds__(256, 2) void gemm_gi(
    const f16* __restrict__ A, const f16* __restrict__ Wf, const f16* __restrict__ Wr,
    const float* __restrict__ bf, const float* __restrict__ br,
    f16* __restrict__ gi, int K)
{
    __shared__ f16 As[128 * 72];
    __shared__ f16 Bs[128 * 72];
    const int m0 = blockIdx.x * 128;
    const int n0g = blockIdx.y * 128;
    const int dir = (n0g >= NH3) ? 1 : 0;
    const f16* __restrict__ W = dir ? Wr : Wf;
    const float* __restrict__ bias = dir ? br : bf;
    const int n0 = n0g - dir * NH3;
    const int tid = threadIdx.x;
    const int lane = tid & 63;
    const int wv = tid >> 6;
    const int wm = wv & 1;
    const int wn = wv >> 1;
    const int srow = tid >> 3;
    const int scol = (tid & 7) * 8;

    float4v acc[4][4] = {};
    for (int kb = 0; kb < K; kb += 64) {
        int4 av[4], bv[4];
#pragma unroll
        for (int i = 0; i < 4; i++) {
            av[i] = *(const int4*)(A + (size_t)(m0 + srow + i * 32) * K + kb + scol);
            bv[i] = *(const int4*)(W + (size_t)(n0 + srow + i * 32) * K + kb + scol);
        }
        __syncthreads();
#pragma unroll
        for (int i = 0; i < 4; i++) {
            *(int4*)(As + (srow + i * 32) * 72 + scol) = av[i];
            *(int4*)(Bs + (srow + i * 32) * 72 + scol) = bv[i];
        }
        __syncthreads();
#pragma unroll
        for (int ks = 0; ks < 2; ks++) {
            half8 af[4], bw[4];
#pragma unroll
            for (int i = 0; i < 4; i++) {
                af[i] = *(const half8*)(As + (wm * 64 + i * 16 + (lane & 15)) * 72 + ks * 32 + (lane >> 4) * 8);
                bw[i] = *(const half8*)(Bs + (wn * 64 + i * 16 + (lane & 15)) * 72 + ks * 32 + (lane >> 4) * 8);
            }
#pragma unroll
            for (int i = 0; i < 4; i++)
#pragma unroll
                for (int j = 0; j < 4; j++)
                    acc[i][j] = __builtin_amdgcn_mfma_f32_16x16x32_f16(af[i], bw[j], acc[i][j], 0, 0, 0);
        }
    }
    f16* __restrict__ gid = gi + (size_t)dir * NM * NH3;
#pragma unroll
    for (int i = 0; i < 4; i++) {
        const int m = m0 + wm * 64 + i * 16 + ((lane >> 4) << 2);
#pragma unroll
        for (int j = 0; j < 4; j++) {
            const int n = n0 + wn * 64 + j * 16 + (lane & 15);
            const float b = bias[n];
#pragma unroll
            for (int r = 0; r < 4; r++)
                gid[(size_t)(m + r) * NH3 + n] = (f16)(acc[i][j][r] + b);
        }
    }
}

// ---------------- device-coherent helpers ----------------
__device__ __forceinline__ unsigned long long ld_dev_u64(const void* p) {
    return __hip_atomic_load((const unsigned long long*)p,
                             __ATOMIC_RELAXED, __HIP_MEMORY_SCOPE_AGENT);
}
__device__ __forceinline__ void st_dev_u64(void* p, unsigned long long v) {
    __hip_atomic_store((unsigned long long*)p, v,
                       __ATOMIC_RELAXED, __HIP_MEMORY_SCOPE_AGENT);
}

union U4H8 { unsigned u[4]; half8 h; };

// ---------------- GRU scan ----------------
// R5 base (proven fastest): 64 blocks (blockIdx/32 = dir, blockIdx%32 = 16-col slice),
// 128 threads (2 waves). Tagged-payload exchange: detection completes WITH the data.
// R10 additions (both strictly additive to the proven machinery):
//  (1) canary gate: spin on 16 canary chunks (1/3 traffic) with s_sleep throttle --
//      consumers arrive EARLY (R8 finding), so full-sweep spinning is congestion that
//      delays the producers' own stores; verify-all full sweep unchanged after.
//  (2) double-buffered transpose tile (proven in R8): removes the 2nd barrier whose
//      vmcnt(0) drained the publish stores on the critical path.
__global__ __launch_bounds__(128, 1) void gru_scan(
    const f16* __restrict__ gi,      // [2][NM][1536]
    const f16* __restrict__ Whf, const f16* __restrict__ Whr,   // [1536][512]
    const float* __restrict__ bhf, const float* __restrict__ bhr,
    unsigned long long* __restrict__ HB,   // [2][2][32][32][6] tagged chunks
    f16* __restrict__ y16,           // layer0 output (fp16) or nullptr
    float* __restrict__ y32,         // layer1 output (fp32, d_out) or nullptr
    float* __restrict__ hlast)       // [2][NB][NH] fp32
{
    __shared__ f16 Wlds[48 * 520];
    __shared__ unsigned short Tt[2][32][18];   // double-buffered transpose tile
    const int d = blockIdx.x >> 5;
    const int cs = blockIdx.x & 31;
    const int c0 = cs * 16;
    const f16* __restrict__ W = d ? Whr : Whf;
    const float* __restrict__ bhh = d ? bhr : bhf;
    const int tid = threadIdx.x;
    const int lane = tid & 63;
    const int mt = tid >> 6;         // wave index = batch half

    // stage W_hh rows {g*512 + c0 + j} into LDS (row-major [48][520], padded)
    for (int c = tid; c < 48 * 64; c += 128) {
        const int row = c >> 6;
        const int off = (c & 63) * 8;
        const int g = row >> 4, j = row & 15;
        *(int4*)(Wlds + row * 520 + off) = *(const int4*)(W + (size_t)(g * 512 + c0 + j) * 512 + off);
    }
    if (tid < 64) {   // zero pad columns of both Tt buffers
        Tt[0][tid >> 1][16 + (tid & 1)] = 0;
        Tt[1][tid >> 1][16 + (tid & 1)] = 0;
    }
    const int cl = c0 + (lane & 15);
    float bh[3];
#pragma unroll
    for (int g = 0; g < 3; g++) bh[g] = bhh[g * 512 + cl];
    __syncthreads();

    // hoist B fragments (step-invariant): 48 x half8
    half8 bfr[16][3];
#pragma unroll
    for (int kk = 0; kk < 16; kk++)
#pragma unroll
        for (int g = 0; g < 3; g++)
            bfr[kk][g] = *(const half8*)(Wlds + (g * 16 + (lane & 15)) * 520 + kk * 32 + (lane >> 4) * 8);

    const f16* __restrict__ giD = gi + (size_t)d * NM * NH3;
    const int bA = mt * 16 + (lane & 15);          // A-frag row (batch)
    const int bC = mt * 16 + ((lane >> 4) << 2);   // C-frag batch base (+r)
    const int g0 = (lane >> 4) & 1;                // which 8-half group
    const int csBase = (lane >> 4) >> 1;           // slice parity
    const int chunkBase = (csBase * 32 + bA) * 6 + g0 * 3;

    float h32[4] = {0.f, 0.f, 0.f, 0.f};
    float gif[3][4];
    {
        const int te = d ? (NT - 1) : 0;
#pragma unroll
        for (int r = 0; r < 4; r++) {
            const f16* p = giD + ((size_t)(bC + r) * NT + te) * NH3;
#pragma unroll
            for (int g = 0; g < 3; g++) gif[g][r] = (float)p[g * 512 + cl];
        }
    }

    for (int t = 0; t < NT; t++) {
        const int te = d ? (NT - 1 - t) : t;
        const unsigned long long* const HBr = HB + (size_t)(d * 2 + (t & 1)) * 6144;
        const unsigned tagT = (unsigned)t & 0xffffu;

        // -------- (1) canary gate: chunk ci=0 of each kk, throttled --------
        while (true) {
            unsigned bad = 0;
#pragma unroll
            for (int kk = 0; kk < 16; kk++)
                bad |= (unsigned)(ld_dev_u64(HBr + chunkBase + kk * 384) >> 48) ^ tagT;
            if (__all(bad == 0)) break;
            __builtin_amdgcn_s_sleep(2);
        }

        // -------- full tagged sweep + verify (R5 loop, unchanged safety) --------
        unsigned long long ch[16][3];
        bool ok;
        do {
#pragma unroll
            for (int kk = 0; kk < 16; kk++) {
                const unsigned long long* p = HBr + chunkBase + kk * 384;
                ch[kk][0] = ld_dev_u64(p);
                ch[kk][1] = ld_dev_u64(p + 1);
                ch[kk][2] = ld_dev_u64(p + 2);
            }
            unsigned bad = 0;
#pragma unroll
            for (int kk = 0; kk < 16; kk++)
#pragma unroll
                for (int ci = 0; ci < 3; ci++)
                    bad |= (unsigned)(ch[kk][ci] >> 48) ^ tagT;
            ok = __all(bad == 0);
            if (!ok) __builtin_amdgcn_s_sleep(1);
        } while (!ok);

        // -------- extract fragments + MFMA --------
        float4v acc[3] = {};
#pragma unroll
        for (int kk = 0; kk < 16; kk++) {
            const unsigned A_lo = (unsigned)ch[kk][0], A_hi = (unsigned)(ch[kk][0] >> 32);
            const unsigned B_lo = (unsigned)ch[kk][1], B_hi = (unsigned)(ch[kk][1] >> 32);
            const unsigned C_lo = (unsigned)ch[kk][2];
            U4H8 u;
            u.u[0] = A_lo;
            u.u[1] = (A_hi & 0xffffu) | (B_lo << 16);
            u.u[2] = (B_lo >> 16) | (B_hi << 16);
            u.u[3] = C_lo;
#pragma unroll
            for (int g = 0; g < 3; g++)
                acc[g] = __builtin_amdgcn_mfma_f32_16x16x32_f16(u.h, bfr[kk][g], acc[g], 0, 0, 0);
        }

        float hnew[4]; f16 hnew16[4];
#pragma unroll
        for (int r = 0; r < 4; r++) {
            const float hr = acc[0][r] + bh[0];
            const float hz = acc[1][r] + bh[1];
            const float hn = acc[2][r] + bh[2];
            const float rg = 1.f / (1.f + __expf(-(gif[0][r] + hr)));
            const float zg = 1.f / (1.f + __expf(-(gif[1][r] + hz)));
            const float x2 = gif[2][r] + rg * hn;
            const float e2 = __expf(x2 + x2);
            const float ng = 1.f - 2.f / (e2 + 1.f);
            const float h = (1.f - zg) * ng + zg * h32[r];
            h32[r] = h; hnew[r] = h; hnew16[r] = (f16)h;
        }

        const bool more = (t + 1 < NT);
        if (more) {
            // -------- (2) publish h_{t+1}: dbuf LDS transpose -> 192 tagged u64 -----
            const int tb = (t + 1) & 1;
#pragma unroll
            for (int r = 0; r < 4; r++)
                Tt[tb][bC + r][lane & 15] = __builtin_bit_cast(unsigned short, hnew16[r]);
            __syncthreads();   // Tt[tb] complete (only barrier in the loop)
            {
                const unsigned long long tagw = ((unsigned long long)((t + 1) & 0xffff)) << 48;
                unsigned long long* const HBw =
                    HB + (size_t)(d * 2 + tb) * 6144 + (size_t)cs * 192;
#pragma unroll
                for (int s = 0; s < 2; s++) {
                    const int cf = tid + s * 128;
                    if (cf < 192) {
                        const int b = cf / 6, c = cf % 6;
                        const int j0 = (c / 3) * 8 + (c % 3) * 3;
                        const unsigned long long h0 = Tt[tb][b][j0];
                        const unsigned long long h1 = Tt[tb][b][j0 + 1];
                        const unsigned long long h2 = Tt[tb][b][j0 + 2];
                        st_dev_u64(HBw + cf, h0 | (h1 << 16) | (h2 << 32) | tagw);
                    }
                }
            }
            // no second barrier: next iteration writes Tt[tb^1] (double buffer)
        }
        // -------- y output (nontemporal streaming; overlaps peers' polling) --------
#pragma unroll
        for (int r = 0; r < 4; r++) {
            const size_t yoff = ((size_t)(bC + r) * NT + te) * (2 * NH) + d * NH + cl;
            if (y16) __builtin_nontemporal_store(hnew16[r], &y16[yoff]);
            else     __builtin_nontemporal_store(hnew[r], &y32[yoff]);
        }
        if (t == NT - 1) {
#pragma unroll
            for (int r = 0; r < 4; r++)
                hlast[d * NB * NH + (bC + r) * NH + cl] = hnew[r];
        }
        if (more) {
            // prefetch gi for t+1 (plain cached; in flight during next poll)
            const int te2 = d ? (NT - 2 - t) : (t + 1);
#pragma unroll
            for (int r = 0; r < 4; r++) {
                const f16* p = giD + ((size_t)(bC + r) * NT + te2) * NH3;
#pragma unroll
                for (int g = 0; g < 3; g++) gif[g][r] = (float)p[g * 512 + cl];
            }
        }
    }
}

extern "C" void kernel_launch(void* const* d_in, const int* in_sizes, int n_in,
                              void* d_out, int out_size, void* d_ws, size_t ws_size,
                              hipStream_t stream) {
    (void)in_sizes; (void)n_in; (void)out_size; (void)ws_size;
    const float* X     = (const float*)d_in[0];
    const float* wih0f = (const float*)d_in[1];
    const float* bih0f = (const float*)d_in[2];
    const float* whh0f = (const float*)d_in[3];
    const float* bhh0f = (const float*)d_in[4];
    const float* wih0r = (const float*)d_in[5];
    const float* bih0r = (const float*)d_in[6];
    const float* whh0r = (const float*)d_in[7];
    const float* bhh0r = (const float*)d_in[8];
    const float* wih1f = (const float*)d_in[9];
    const float* bih1f = (const float*)d_in[10];
    const float* whh1f = (const float*)d_in[11];
    const float* bhh1f = (const float*)d_in[12];
    const float* wih1r = (const float*)d_in[13];
    const float* bih1r = (const float*)d_in[14];
    const float* whh1r = (const float*)d_in[15];
    const float* bhh1r = (const float*)d_in[16];

    char* ws = (char*)d_ws;
    f16* Xh   = (f16*)(ws + 0ull);
    f16* Wi0f = (f16*)(ws + 33554432ull);
    f16* Wi0r = (f16*)(ws + 35127296ull);
    f16* Wh0f = (f16*)(ws + 36700160ull);
    f16* Wh0r = (f16*)(ws + 38273024ull);
    f16* Wi1f = (f16*)(ws + 39845888ull);
    f16* Wi1r = (f16*)(ws + 42991616ull);
    f16* Wh1f = (f16*)(ws + 46137344ull);
    f16* Wh1r = (f16*)(ws + 47710208ull);
    f16* Y0h  = (f16*)(ws + 49283072ull);
    unsigned long long* HBu = (unsigned long long*)(ws + 116391936ull);  // 192KB
    f16* GI   = (f16*)(ws + 116655104ull);
    float* out = (float*)d_out;

    auto cvt = [&](const float* s, f16* d, size_t n) {
        int n4 = (int)(n / 4);
        int grid = (n4 + 255) / 256; if (grid > 4096) grid = 4096;
        cvt_f16<<<grid, 256, 0, stream>>>(s, d, n4);
    };
    cvt(X,     Xh,   (size_t)NM * NH);
    cvt(wih0f, Wi0f, (size_t)NH3 * NH);
    cvt(wih0r, Wi0r, (size_t)NH3 * NH);
    cvt(whh0f, Wh0f, (size_t)NH3 * NH);
    cvt(whh0r, Wh0r, (size_t)NH3 * NH);
    cvt(wih1f, Wi1f, (size_t)NH3 * 2 * NH);
    cvt(wih1r, Wi1r, (size_t)NH3 * 2 * NH);
    cvt(whh1f, Wh1f, (size_t)NH3 * NH);
    cvt(whh1r, Wh1r, (size_t)NH3 * NH);

    const size_t OUT0 = (size_t)NM * 2 * NH;   // 33,554,432 floats

    // Layer 0
    init_hb<<<96, 256, 0, stream>>>(HBu);
    gemm_gi<<<dim3(NM / 128, 24), 256, 0, stream>>>(Xh, Wi0f, Wi0r, bih0f, bih0r, GI, NH);
    gru_scan<<<64, 128, 0, stream>>>(GI, Wh0f, Wh0r, bhh0f, bhh0r,
                                     HBu, Y0h, nullptr, out + OUT0);
    // Layer 1 (reset tags, reuse HB)
    init_hb<<<96, 256, 0, stream>>>(HBu);
    gemm_gi<<<dim3(NM / 128, 24), 256, 0, stream>>>(Y0h, Wi1f, Wi1r, bih1f, bih1r, GI, 2 * NH);
    gru_scan<<<64, 128, 0, stream>>>(GI, Wh1f, Wh1r, bhh1f, bhh1r,
                                     HBu, nullptr, out, out + OUT0 + 2 * NB * NH);
}

// Round 11
// 8075.763 us; speedup vs baseline: 2.0184x; 1.5160x over previous
//
#include <hip/hip_runtime.h>

typedef _Float16 f16;
typedef _Float16 half8 __attribute__((ext_vector_type(8)));
typedef _Float16 half4v __attribute__((ext_vector_type(4)));
typedef float float4v __attribute__((ext_vector_type(4)));

constexpr int NB = 32;            // batch
constexpr int NT = 1024;          // time
constexpr int NH = 512;           // hidden
constexpr int NH3 = 1536;
constexpr int NM = NB * NT;       // 32768 rows

// h-exchange: HB[dir][buf][batch 32][colq 128] u64. One u64 = 4 consecutive f16
// h-cols of one batch; generation tag in 2 stolen LSBs (bit0 <- t&1, bit16 <- (t>>1)&1).
// One aligned 8B store => tag+data atomic. 128KB total; re-zeroed between layers
// (zeros == h0 with tag (0,0) == gen 0).
constexpr int HB_U64 = 2 * 2 * 32 * 128;   // 16384

__global__ void init_hb(unsigned long long* __restrict__ hb) {
    int i = blockIdx.x * 256 + threadIdx.x;
    if (i < HB_U64) hb[i] = 0ull;
}

// ---------------- fp32 -> fp16 convert ----------------
__global__ void cvt_f16(const float* __restrict__ src, f16* __restrict__ dst, int n4) {
    int i = blockIdx.x * blockDim.x + threadIdx.x;
    int stride = gridDim.x * blockDim.x;
    for (; i < n4; i += stride) {
        float4v v = *(const float4v*)(src + 4 * (size_t)i);
        half4v h;
        h[0] = (f16)v[0]; h[1] = (f16)v[1]; h[2] = (f16)v[2]; h[3] = (f16)v[3];
        *(half4v*)(dst + 4 * (size_t)i) = h;
    }
}

// ---------------- gi GEMM (unchanged) ----------------
__global__ __launch_bounds__(256, 2) void gemm_gi(
    const f16* __restrict__ A, const f16* __restrict__ Wf, const f16* __restrict__ Wr,
    const float* __restrict__ bf, const float* __restrict__ br,
    f16* __restrict__ gi, int K)
{
    __shared__ f16 As[128 * 72];
    __shared__ f16 Bs[128 * 72];
    const int m0 = blockIdx.x * 128;
    const int n0g = blockIdx.y * 128;
    const int dir = (n0g >= NH3) ? 1 : 0;
    const f16* __restrict__ W = dir ? Wr : Wf;
    const float* __restrict__ bias = dir ? br : bf;
    const int n0 = n0g - dir * NH3;
    const int tid = threadIdx.x;
    const int lane = tid & 63;
    const int wv = tid >> 6;
    const int wm = wv & 1;
    const int wn = wv >> 1;
    const int srow = tid >> 3;
    const int scol = (tid & 7) * 8;

    float4v acc[4][4] = {};
    for (int kb = 0; kb < K; kb += 64) {
        int4 av[4], bv[4];
#pragma unroll
        for (int i = 0; i < 4; i++) {
            av[i] = *(const int4*)(A + (size_t)(m0 + srow + i * 32) * K + kb + scol);
            bv[i] = *(const int4*)(W + (size_t)(n0 + srow + i * 32) * K + kb + scol);
        }
        __syncthreads();
#pragma unroll
        for (int i = 0; i < 4; i++) {
            *(int4*)(As + (srow + i * 32) * 72 + scol) = av[i];
            *(int4*)(Bs + (srow + i * 32) * 72 + scol) = bv[i];
        }
        __syncthreads();
#pragma unroll
        for (int ks = 0; ks < 2; ks++) {
            half8 af[4], bw[4];
#pragma unroll
            for (int i = 0; i < 4; i++) {
                af[i] = *(const half8*)(As + (wm * 64 + i * 16 + (lane & 15)) * 72 + ks * 32 + (lane >> 4) * 8);
                bw[i] = *(const half8*)(Bs + (wn * 64 + i * 16 + (lane & 15)) * 72 + ks * 32 + (lane >> 4) * 8);
            }
#pragma unroll
            for (int i = 0; i < 4; i++)
#pragma unroll
                for (int j = 0; j < 4; j++)
                    acc[i][j] = __builtin_amdgcn_mfma_f32_16x16x32_f16(af[i], bw[j], acc[i][j], 0, 0, 0);
        }
    }
    f16* __restrict__ gid = gi + (size_t)dir * NM * NH3;
#pragma unroll
    for (int i = 0; i < 4; i++) {
        const int m = m0 + wm * 64 + i * 16 + ((lane >> 4) << 2);
#pragma unroll
        for (int j = 0; j < 4; j++) {
            const int n = n0 + wn * 64 + j * 16 + (lane & 15);
            const float b = bias[n];
#pragma unroll
            for (int r = 0; r < 4; r++)
                gid[(size_t)(m + r) * NH3 + n] = (f16)(acc[i][j][r] + b);
        }
    }
}

// ---------------- device-coherent helpers ----------------
__device__ __forceinline__ unsigned long long ld_dev_u64(const void* p) {
    return __hip_atomic_load((const unsigned long long*)p,
                             __ATOMIC_RELAXED, __HIP_MEMORY_SCOPE_AGENT);
}
__device__ __forceinline__ void st_dev_u64(void* p, unsigned long long v) {
    __hip_atomic_store((unsigned long long*)p, v,
                       __ATOMIC_RELAXED, __HIP_MEMORY_SCOPE_AGENT);
}

union U2H8 { unsigned long long u[2]; half8 h; };

// ---------------- GRU scan ----------------
// 64 blocks (blockIdx/32 = dir, blockIdx%32 = 16-col slice), 128 threads (2 waves).
// TRANSPOSED MFMA: A-operand = W rows (16 output cols), B-operand = h (16 batches).
// A/B per-lane fragment layouts are symmetric, so the register data is identical to
// R5 -- only the operand order swaps, transposing C. Each lane then owns 4 CONSECUTIVE
// output cols x 1 batch = exactly one u64 of 4 f16: publish = single coherent store,
// no LDS transpose, no barrier (R5's entire publish machinery deleted). Tag = 2 stolen
// LSBs (mod-4 generation; only possible stale occupant is gen t-2, which always
// differs in bit16). Consumer fragments are a zero-ALU bitcast of 2 u64s.
__global__ __launch_bounds__(128, 1) void gru_scan(
    const f16* __restrict__ gi,      // [2][NM][1536]
    const f16* __restrict__ Whf, const f16* __restrict__ Whr,   // [1536][512]
    const float* __restrict__ bhf, const float* __restrict__ bhr,
    unsigned long long* __restrict__ HB,   // [2][2][32][128] u64
    f16* __restrict__ y16,           // layer0 output (fp16) or nullptr
    float* __restrict__ y32,         // layer1 output (fp32, d_out) or nullptr
    float* __restrict__ hlast)       // [2][NB][NH] fp32
{
    __shared__ f16 Wlds[48 * 520];
    const int d = blockIdx.x >> 5;
    const int cs = blockIdx.x & 31;
    const int c0 = cs * 16;
    const f16* __restrict__ W = d ? Whr : Whf;
    const float* __restrict__ bhh = d ? bhr : bhf;
    const int tid = threadIdx.x;
    const int lane = tid & 63;
    const int mt = tid >> 6;         // wave index = batch half

    // stage W_hh rows {g*512 + c0 + j} into LDS (row-major [48][520], padded)
    for (int c = tid; c < 48 * 64; c += 128) {
        const int row = c >> 6;
        const int off = (c & 63) * 8;
        const int g = row >> 4, j = row & 15;
        *(int4*)(Wlds + row * 520 + off) = *(const int4*)(W + (size_t)(g * 512 + c0 + j) * 512 + off);
    }
    __syncthreads();

    // W fragments (A-operand): lane holds W[c0 + (lane&15)][k-slice] -- identical
    // data/loads to R5's bfr; role changes to A.
    half8 bfr[16][3];
#pragma unroll
    for (int kk = 0; kk < 16; kk++)
#pragma unroll
        for (int g = 0; g < 3; g++)
            bfr[kk][g] = *(const half8*)(Wlds + (g * 16 + (lane & 15)) * 520 + kk * 32 + (lane >> 4) * 8);

    const int bP = mt * 16 + (lane & 15);   // owned batch (B-col = C-col)
    const int q  = lane >> 4;               // col-quad 0..3
    const int cP = c0 + q * 4;              // first owned output col (C-rows q*4+r)

    float bh[3][4];
#pragma unroll
    for (int g = 0; g < 3; g++) {
        const float4v bv = *(const float4v*)(bhh + g * 512 + cP);
#pragma unroll
        for (int r = 0; r < 4; r++) bh[g][r] = bv[r];
    }

    const f16* __restrict__ giD = gi + (size_t)d * NM * NH3;
    unsigned long long* const HBd = HB + (size_t)d * 2 * 32 * 128;

    float h32[4] = {0.f, 0.f, 0.f, 0.f};
    float gif[3][4];
    {
        const int te = d ? (NT - 1) : 0;
        const f16* p = giD + ((size_t)bP * NT + te) * NH3 + cP;
#pragma unroll
        for (int g = 0; g < 3; g++) {
            const half4v v = *(const half4v*)(p + g * 512);
#pragma unroll
            for (int r = 0; r < 4; r++) gif[g][r] = (float)v[r];
        }
    }

    for (int t = 0; t < NT; t++) {
        const int te = d ? (NT - 1 - t) : t;
        const unsigned long long* const HBr =
            HBd + (size_t)(t & 1) * 32 * 128 + (size_t)bP * 128;
        const unsigned long long tagpat =
            (unsigned long long)((unsigned)(t & 1)) |
            ((unsigned long long)((unsigned)((t >> 1) & 1)) << 16);

        // -------- poll: 32 u64 (own batch row) until all tag bits match gen t ------
        unsigned long long ch[16][2];
        bool ok;
        do {
#pragma unroll
            for (int kk = 0; kk < 16; kk++) {
                ch[kk][0] = ld_dev_u64(HBr + kk * 8 + q * 2);
                ch[kk][1] = ld_dev_u64(HBr + kk * 8 + q * 2 + 1);
            }
            unsigned long long bad = 0;
#pragma unroll
            for (int kk = 0; kk < 16; kk++)
#pragma unroll
                for (int c = 0; c < 2; c++)
                    bad |= (ch[kk][c] ^ tagpat) & 0x0000000000010001ull;
            ok = __all(bad == 0);
        } while (!ok);

        // -------- fragments (zero-ALU bitcast) + transposed MFMA --------
        float4v acc[3] = {};
#pragma unroll
        for (int kk = 0; kk < 16; kk++) {
            U2H8 u;
            u.u[0] = ch[kk][0];
            u.u[1] = ch[kk][1];
#pragma unroll
            for (int g = 0; g < 3; g++)
                acc[g] = __builtin_amdgcn_mfma_f32_16x16x32_f16(bfr[kk][g], u.h, acc[g], 0, 0, 0);
        }

        float hnew[4]; f16 hnew16[4];
#pragma unroll
        for (int r = 0; r < 4; r++) {
            const float hr = acc[0][r] + bh[0][r];
            const float hz = acc[1][r] + bh[1][r];
            const float hn = acc[2][r] + bh[2][r];
            const float rg = 1.f / (1.f + __expf(-(gif[0][r] + hr)));
            const float zg = 1.f / (1.f + __expf(-(gif[1][r] + hz)));
            const float x2 = gif[2][r] + rg * hn;
            const float e2 = __expf(x2 + x2);
            const float ng = 1.f - 2.f / (e2 + 1.f);
            const float h = (1.f - zg) * ng + zg * h32[r];
            h32[r] = h; hnew[r] = h; hnew16[r] = (f16)h;
        }

        const bool more = (t + 1 < NT);
        if (more) {
            // -------- publish: ONE tagged u64 store per thread, immediately --------
            unsigned long long pk =
                (unsigned long long)__builtin_bit_cast(unsigned short, hnew16[0]) |
                ((unsigned long long)__builtin_bit_cast(unsigned short, hnew16[1]) << 16) |
                ((unsigned long long)__builtin_bit_cast(unsigned short, hnew16[2]) << 32) |
                ((unsigned long long)__builtin_bit_cast(unsigned short, hnew16[3]) << 48);
            pk = (pk & ~0x0000000000010001ull) |
                 (unsigned long long)((unsigned)((t + 1) & 1)) |
                 ((unsigned long long)((unsigned)(((t + 1) >> 1) & 1)) << 16);
            st_dev_u64(HBd + (size_t)((t + 1) & 1) * 32 * 128 + (size_t)bP * 128 + (cP >> 2), pk);
        }
        // -------- y output (clean values, vectorized nontemporal) --------
        {
            const size_t yoff = ((size_t)bP * NT + te) * (2 * NH) + d * NH + cP;
            if (y16) {
                const unsigned long long yv =
                    (unsigned long long)__builtin_bit_cast(unsigned short, hnew16[0]) |
                    ((unsigned long long)__builtin_bit_cast(unsigned short, hnew16[1]) << 16) |
                    ((unsigned long long)__builtin_bit_cast(unsigned short, hnew16[2]) << 32) |
                    ((unsigned long long)__builtin_bit_cast(unsigned short, hnew16[3]) << 48);
                __builtin_nontemporal_store(yv, (unsigned long long*)(y16 + yoff));
            } else {
                float4v yv; yv[0] = hnew[0]; yv[1] = hnew[1]; yv[2] = hnew[2]; yv[3] = hnew[3];
                __builtin_nontemporal_store(yv, (float4v*)(y32 + yoff));
            }
        }
        if (t == NT - 1) {
            float4v hv; hv[0] = hnew[0]; hv[1] = hnew[1]; hv[2] = hnew[2]; hv[3] = hnew[3];
            *(float4v*)(hlast + d * NB * NH + bP * NH + cP) = hv;
        }
        if (more) {
            // prefetch gi for t+1 (plain cached; in flight during next poll)
            const int te2 = d ? (NT - 2 - t) : (t + 1);
            const f16* p = giD + ((size_t)bP * NT + te2) * NH3 + cP;
#pragma unroll
            for (int g = 0; g < 3; g++) {
                const half4v v = *(const half4v*)(p + g * 512);
#pragma unroll
                for (int r = 0; r < 4; r++) gif[g][r] = (float)v[r];
            }
        }
    }
}

extern "C" void kernel_launch(void* const* d_in, const int* in_sizes, int n_in,
                              void* d_out, int out_size, void* d_ws, size_t ws_size,
                              hipStream_t stream) {
    (void)in_sizes; (void)n_in; (void)out_size; (void)ws_size;
    const float* X     = (const float*)d_in[0];
    const float* wih0f = (const float*)d_in[1];
    const float* bih0f = (const float*)d_in[2];
    const float* whh0f = (const float*)d_in[3];
    const float* bhh0f = (const float*)d_in[4];
    const float* wih0r = (const float*)d_in[5];
    const float* bih0r = (const float*)d_in[6];
    const float* whh0r = (const float*)d_in[7];
    const float* bhh0r = (const float*)d_in[8];
    const float* wih1f = (const float*)d_in[9];
    const float* bih1f = (const float*)d_in[10];
    const float* whh1f = (const float*)d_in[11];
    const float* bhh1f = (const float*)d_in[12];
    const float* wih1r = (const float*)d_in[13];
    const float* bih1r = (const float*)d_in[14];
    const float* whh1r = (const float*)d_in[15];
    const float* bhh1r = (const float*)d_in[16];

    char* ws = (char*)d_ws;
    f16* Xh   = (f16*)(ws + 0ull);
    f16* Wi0f = (f16*)(ws + 33554432ull);
    f16* Wi0r = (f16*)(ws + 35127296ull);
    f16* Wh0f = (f16*)(ws + 36700160ull);
    f16* Wh0r = (f16*)(ws + 38273024ull);
    f16* Wi1f = (f16*)(ws + 39845888ull);
    f16* Wi1r = (f16*)(ws + 42991616ull);
    f16* Wh1f = (f16*)(ws + 46137344ull);
    f16* Wh1r = (f16*)(ws + 47710208ull);
    f16* Y0h  = (f16*)(ws + 49283072ull);
    unsigned long long* HBu = (unsigned long long*)(ws + 116391936ull);  // 128KB
    f16* GI   = (f16*)(ws + 116655104ull);
    float* out = (float*)d_out;

    auto cvt = [&](const float* s, f16* d, size_t n) {
        int n4 = (int)(n / 4);
        int grid = (n4 + 255) / 256; if (grid > 4096) grid = 4096;
        cvt_f16<<<grid, 256, 0, stream>>>(s, d, n4);
    };
    cvt(X,     Xh,   (size_t)NM * NH);
    cvt(wih0f, Wi0f, (size_t)NH3 * NH);
    cvt(wih0r, Wi0r, (size_t)NH3 * NH);
    cvt(whh0f, Wh0f, (size_t)NH3 * NH);
    cvt(whh0r, Wh0r, (size_t)NH3 * NH);
    cvt(wih1f, Wi1f, (size_t)NH3 * 2 * NH);
    cvt(wih1r, Wi1r, (size_t)NH3 * 2 * NH);
    cvt(whh1f, Wh1f, (size_t)NH3 * NH);
    cvt(whh1r, Wh1r, (size_t)NH3 * NH);

    const size_t OUT0 = (size_t)NM * 2 * NH;   // 33,554,432 floats

    // Layer 0
    init_hb<<<64, 256, 0, stream>>>(HBu);
    gemm_gi<<<dim3(NM / 128, 24), 256, 0, stream>>>(Xh, Wi0f, Wi0r, bih0f, bih0r, GI, NH);
    gru_scan<<<64, 128, 0, stream>>>(GI, Wh0f, Wh0r, bhh0f, bhh0r,
                                     HBu, Y0h, nullptr, out + OUT0);
    // Layer 1 (reset tags to gen 0, reuse HB)
    init_hb<<<64, 256, 0, stream>>>(HBu);
    gemm_gi<<<dim3(NM / 128, 24), 256, 0, stream>>>(Y0h, Wi1f, Wi1r, bih1f, bih1r, GI, 2 * NH);
    gru_scan<<<64, 128, 0, stream>>>(GI, Wh1f, Wh1r, bhh1f, bhh1r,
                                     HBu, nullptr, out, out + OUT0 + 2 * NB * NH);
}